// Round 14
// baseline (298.960 us; speedup 1.0000x reference)
//
#include <hip/hip_runtime.h>
#include <hip/hip_bf16.h>

typedef __attribute__((ext_vector_type(8))) short short8;
typedef __attribute__((ext_vector_type(4))) float f32x4;

#define MFMA_B16(a, b, c) __builtin_amdgcn_mfma_f32_16x16x32_bf16((a), (b), (c), 0, 0, 0)

__device__ __forceinline__ float bf2f(unsigned short u) {
    union { unsigned int i; float f; } v; v.i = ((unsigned int)u) << 16; return v.f;
}
__device__ __forceinline__ unsigned short f2bf(float f) {
    union { float f; unsigned int i; } v; v.f = f;
    unsigned int r = v.i + 0x7fffu + ((v.i >> 16) & 1u);
    return (unsigned short)(r >> 16);
}
// fast HW transcendentals; gate scales folded into weights at convert time.
__device__ __forceinline__ float rcp_f(float x) { return __builtin_amdgcn_rcpf(x); }
__device__ __forceinline__ float sigm_pre(float x) {      // x = -log2(e)*(...)
    return rcp_f(1.0f + __builtin_amdgcn_exp2f(x));
}
__device__ __forceinline__ float tanh_pre(float x) {      // x = 2*log2(e)*(...)
    return 1.0f - 2.0f * rcp_f(__builtin_amdgcn_exp2f(x) + 1.0f);
}

__device__ __forceinline__ bool probe_bf16(const unsigned short* p, int tid, int* s_cnt) {
    if (tid == 0) *s_cnt = 0;
    __syncthreads();
    unsigned short s = p[tid & 255];
    int e = (s >> 7) & 0xFF;
    if (tid < 256 && e >= 117 && e <= 137) atomicAdd(s_cnt, 1);
    __syncthreads();
    return *s_cnt >= 200;
}

// ---------------------------------------------------------------------------
struct WArgs {
    const void* src[20];
    int off[21];
};

__global__ __launch_bounds__(256)
void convert_w(WArgs a, unsigned short* __restrict__ arena,
               const unsigned short* __restrict__ probe)
{
    __shared__ int cnt;
    const bool bf = probe_bf16(probe, threadIdx.x, &cnt);
    const int total = a.off[20];
    for (int i = blockIdx.x * 256 + threadIdx.x; i < total; i += gridDim.x * 256) {
        int t = 0;
        while (t < 19 && i >= a.off[t + 1]) ++t;
        const int local = i - a.off[t];
        float v = bf ? bf2f(((const unsigned short*)a.src[t])[local])
                     : ((const float*)a.src[t])[local];
        if (t < 16) {
            const int col = local % 192;
            if (col < 128) v *= -1.4426950408889634f;
            else if (t >= 8) v *= 2.885390081777927f;
        }
        arena[i] = f2bf(v);
    }
}

// ---------------------------------------------------------------------------
// Layer 1 DUAL: each block owns 32 rows = TWO independent 16-row recurrences
// (A: rows 0..15, B: 16..31) sharing weight registers. One barrier per step.
// grid: (bchunk/32, 2), block 256.
// ---------------------------------------------------------------------------
__global__ __launch_bounds__(256, 1)
void gru1_kernel(const void* __restrict__ X, const void* __restrict__ h0f,
                 const void* __restrict__ h0b, int cb, int bchunk,
                 const unsigned short* __restrict__ Wf, const unsigned short* __restrict__ Uf,
                 const unsigned short* __restrict__ bif, const unsigned short* __restrict__ brf,
                 const unsigned short* __restrict__ Wb, const unsigned short* __restrict__ Ub,
                 const unsigned short* __restrict__ bib, const unsigned short* __restrict__ brb,
                 unsigned short* __restrict__ seq)
{
    const int tid  = threadIdx.x;
    const int lane = tid & 63;
    const int wv   = tid >> 6;
    const int q    = lane >> 4;
    const int ln   = lane & 15;
    const int dir  = blockIdx.y;
    const int lb0  = blockIdx.x * 32;
    const int gb0  = cb + lb0;
    const int u    = wv * 16 + ln;

    const unsigned short* W  = dir ? Wb  : Wf;
    const unsigned short* U  = dir ? Ub  : Uf;
    const unsigned short* bi = dir ? bib : bif;
    const unsigned short* br = dir ? brb : brf;
    const void* h0 = dir ? h0b : h0f;

    __shared__ __align__(16) unsigned short Ah[2][32][72];
    __shared__ __align__(16) unsigned short Ax[2][32][40];
    __shared__ int s_cnt;

    const bool xbf = probe_bf16((const unsigned short*)X, tid, &s_cnt);

    {
        unsigned short* p = &Ax[0][0][0];
        for (int i = tid; i < 2 * 32 * 40; i += 256) p[i] = 0;
    }
    __syncthreads();

    // x(t=0): 32 rows x 9 feats -> hi/lo pairs
    {
        const int tx0 = dir ? 71 : 0;
        for (int i = tid; i < 288; i += 256) {
            int r = i / 9, k = i - 9 * r;
            size_t idx = ((size_t)(gb0 + r) * 72 + tx0) * 9 + k;
            unsigned short hv, lv;
            if (xbf) { hv = ((const unsigned short*)X)[idx]; lv = 0; }
            else { float v = ((const float*)X)[idx]; hv = f2bf(v); lv = f2bf(v - bf2f(hv)); }
            Ax[0][r][2 * k]     = hv;
            Ax[0][r][2 * k + 1] = lv;
        }
    }

    short8 bU[3][2];
    short8 bW[3];
#pragma unroll
    for (int g = 0; g < 3; ++g) {
        const int col = g * 64 + u;
#pragma unroll
        for (int ks = 0; ks < 2; ++ks) {
            short8 f;
#pragma unroll
            for (int j = 0; j < 8; ++j) {
                int kp = ks * 32 + q * 8 + j;
                f[j] = (short)U[(size_t)kp * 192 + col];
            }
            bU[g][ks] = f;
        }
        short8 fw;
#pragma unroll
        for (int j = 0; j < 8; ++j) {
            int kp = q * 8 + j;
            fw[j] = (kp < 18) ? (short)W[(size_t)(kp >> 1) * 192 + col] : (short)0;
        }
        bW[g] = fw;
    }

    const float bz  = bf2f(bi[u])       + bf2f(br[u]);
    const float brg = bf2f(bi[64 + u])  + bf2f(br[64 + u]);
    const float bih = bf2f(bi[128 + u]);
    const float brh = bf2f(br[128 + u]);
    const f32x4 Cz  = {bz,  bz,  bz,  bz};
    const f32x4 Cr  = {brg, brg, brg, brg};
    const f32x4 Chx = {bih, bih, bih, bih};
    const f32x4 Chr = {brh, brh, brh, brh};

    float hA[4], hB[4];
#pragma unroll
    for (int i = 0; i < 4; ++i) {
        int m = q * 4 + i;
        size_t ia = (size_t)(gb0 + m) * 64 + u;
        size_t ib = (size_t)(gb0 + 16 + m) * 64 + u;
        float va = xbf ? bf2f(((const unsigned short*)h0)[ia]) : ((const float*)h0)[ia];
        float vb = xbf ? bf2f(((const unsigned short*)h0)[ib]) : ((const float*)h0)[ib];
        hA[i] = va; hB[i] = vb;
        Ah[0][m][u]      = f2bf(va);
        Ah[0][16 + m][u] = f2bf(vb);
    }

    const int r2 = tid >> 3, c2 = tid & 7;            // 32 rows x 8 int4 = 256
    const int r0x = tid / 9, k0x = tid - 9 * r0x;     // first 256 of 288
    const int i1  = 256 + tid;
    const int r1x = i1 / 9, k1x = i1 - 9 * r1x;       // tid<32: last 32

    // depth-2 x pipeline: preload x(1)
    unsigned short ch0 = 0, cl0 = 0, ch1 = 0, cl1 = 0;
    {
        const int tx = dir ? 70 : 1;
        size_t idx = ((size_t)(gb0 + r0x) * 72 + tx) * 9 + k0x;
        if (xbf) { ch0 = ((const unsigned short*)X)[idx]; cl0 = 0; }
        else { float v = ((const float*)X)[idx]; ch0 = f2bf(v); cl0 = f2bf(v - bf2f(ch0)); }
        if (tid < 32) {
            size_t idx1 = ((size_t)(gb0 + r1x) * 72 + tx) * 9 + k1x;
            if (xbf) { ch1 = ((const unsigned short*)X)[idx1]; cl1 = 0; }
            else { float v = ((const float*)X)[idx1]; ch1 = f2bf(v); cl1 = f2bf(v - bf2f(ch1)); }
        }
    }
    __syncthreads();

#pragma unroll 2
    for (int t = 0; t < 72; ++t) {
        const int cur = t & 1, nb = cur ^ 1;

        // load x(t+2)
        unsigned short fh0 = 0, fl0 = 0, fh1 = 0, fl1 = 0;
        if (t < 70) {
            const int tx = dir ? (69 - t) : (t + 2);
            size_t idx = ((size_t)(gb0 + r0x) * 72 + tx) * 9 + k0x;
            if (xbf) { fh0 = ((const unsigned short*)X)[idx]; fl0 = 0; }
            else { float v = ((const float*)X)[idx]; fh0 = f2bf(v); fl0 = f2bf(v - bf2f(fh0)); }
            if (tid < 32) {
                size_t idx1 = ((size_t)(gb0 + r1x) * 72 + tx) * 9 + k1x;
                if (xbf) { fh1 = ((const unsigned short*)X)[idx1]; fl1 = 0; }
                else { float v = ((const float*)X)[idx1]; fh1 = f2bf(v); fl1 = f2bf(v - bf2f(fh1)); }
            }
        }

        // flush h(t-1): 32 rows x 8 int4 (all 256 threads)
        if (t > 0) {
            const int tw = dir ? (71 - (t - 1)) : (t - 1);
            int4 v = *(const int4*)&Ah[cur][r2][c2 * 8];
            *(int4*)(seq + ((size_t)tw * bchunk + lb0 + r2) * 128 + dir * 64 + c2 * 8) = v;
        }

        // MFMA: problem A then B (independent — compiler interleaves)
        const unsigned short* apA = &Ah[cur][ln][0];
        const unsigned short* apB = &Ah[cur][16 + ln][0];
        short8 a0A = *(const short8*)(apA + q * 8);
        short8 a1A = *(const short8*)(apA + 32 + q * 8);
        short8 axA = *(const short8*)(&Ax[cur][ln][q * 8]);
        short8 a0B = *(const short8*)(apB + q * 8);
        short8 a1B = *(const short8*)(apB + 32 + q * 8);
        short8 axB = *(const short8*)(&Ax[cur][16 + ln][q * 8]);

        f32x4 azA = MFMA_B16(axA, bW[0], Cz);
        azA = MFMA_B16(a0A, bU[0][0], azA);
        azA = MFMA_B16(a1A, bU[0][1], azA);
        f32x4 arA = MFMA_B16(axA, bW[1], Cr);
        arA = MFMA_B16(a0A, bU[1][0], arA);
        arA = MFMA_B16(a1A, bU[1][1], arA);
        f32x4 ahxA = MFMA_B16(axA, bW[2], Chx);
        f32x4 ahrA = MFMA_B16(a0A, bU[2][0], Chr);
        ahrA = MFMA_B16(a1A, bU[2][1], ahrA);

        f32x4 azB = MFMA_B16(axB, bW[0], Cz);
        azB = MFMA_B16(a0B, bU[0][0], azB);
        azB = MFMA_B16(a1B, bU[0][1], azB);
        f32x4 arB = MFMA_B16(axB, bW[1], Cr);
        arB = MFMA_B16(a0B, bU[1][0], arB);
        arB = MFMA_B16(a1B, bU[1][1], arB);
        f32x4 ahxB = MFMA_B16(axB, bW[2], Chx);
        f32x4 ahrB = MFMA_B16(a0B, bU[2][0], Chr);
        ahrB = MFMA_B16(a1B, bU[2][1], ahrB);

#pragma unroll
        for (int i = 0; i < 4; ++i) {
            const int m = q * 4 + i;
            float zA = sigm_pre(azA[i]);
            float rA = sigm_pre(arA[i]);
            float hhA = fmaxf(ahxA[i] + rA * ahrA[i], 0.0f);
            float hnA = hhA + zA * (hA[i] - hhA);
            hA[i] = hnA;
            Ah[nb][m][u] = f2bf(hnA);

            float zB = sigm_pre(azB[i]);
            float rB = sigm_pre(arB[i]);
            float hhB = fmaxf(ahxB[i] + rB * ahrB[i], 0.0f);
            float hnB = hhB + zB * (hB[i] - hhB);
            hB[i] = hnB;
            Ah[nb][16 + m][u] = f2bf(hnB);
        }

        // stage x(t+1) (loaded one full step ago)
        if (t < 71) {
            Ax[nb][r0x][2 * k0x]     = ch0;
            Ax[nb][r0x][2 * k0x + 1] = cl0;
            if (tid < 32) {
                Ax[nb][r1x][2 * k1x]     = ch1;
                Ax[nb][r1x][2 * k1x + 1] = cl1;
            }
        }
        ch0 = fh0; cl0 = fl0; ch1 = fh1; cl1 = fl1;
        __syncthreads();
    }

    // final flush: h(71) in Ah[0]; 32 rows x 8 int4 = 256 threads
    {
        const int tw = dir ? 0 : 71;
        int4 v = *(const int4*)&Ah[0][r2][c2 * 8];
        *(int4*)(seq + ((size_t)tw * bchunk + lb0 + r2) * 128 + dir * 64 + c2 * 8) = v;
    }
}

// ---------------------------------------------------------------------------
// Layer 2 DUAL: two independent 16-row recurrences per block, shared weights.
// Per-lane seq A-frags direct from global, depth-2 prefetch; projections
// pre-barrier. grid (bchunk/32, 2), block 256.
// ---------------------------------------------------------------------------
__global__ __launch_bounds__(256, 1)
void gru2_kernel(const unsigned short* __restrict__ seq, int cb, int bchunk,
                 const unsigned short* __restrict__ W2f, const unsigned short* __restrict__ U2f,
                 const unsigned short* __restrict__ bi2f, const unsigned short* __restrict__ br2f,
                 const unsigned short* __restrict__ W2b, const unsigned short* __restrict__ U2b,
                 const unsigned short* __restrict__ bi2b, const unsigned short* __restrict__ br2b,
                 float* __restrict__ feat)
{
    const int tid  = threadIdx.x;
    const int lane = tid & 63;
    const int wv   = tid >> 6;
    const int q    = lane >> 4;
    const int ln   = lane & 15;
    const int dir  = blockIdx.y;
    const int lb0  = blockIdx.x * 32;
    const int gb0  = cb + lb0;
    const int u    = wv * 16 + ln;

    const unsigned short* W  = dir ? W2b  : W2f;
    const unsigned short* U  = dir ? U2b  : U2f;
    const unsigned short* bi = dir ? bi2b : bi2f;
    const unsigned short* br = dir ? br2b : br2f;

    __shared__ __align__(16) unsigned short Ah[2][32][72];

    {
        unsigned short* p = &Ah[0][0][0];
        for (int i = tid; i < 32 * 72; i += 256) p[i] = 0;
    }

    const long long tstride = (long long)bchunk * 128 * (dir ? -1 : 1);
    const unsigned short* sA = seq + ((size_t)(lb0 + ln)) * 128 + q * 8
                             + (dir ? 71ll * bchunk * 128 : 0);
    const unsigned short* sB = sA + 16 * 128;

    short8 bU[3][2];
    short8 bV[3][4];
#pragma unroll
    for (int g = 0; g < 3; ++g) {
        const int col = g * 64 + u;
#pragma unroll
        for (int ks = 0; ks < 2; ++ks) {
            short8 f;
#pragma unroll
            for (int j = 0; j < 8; ++j) {
                int kp = ks * 32 + q * 8 + j;
                f[j] = (short)U[(size_t)kp * 192 + col];
            }
            bU[g][ks] = f;
        }
#pragma unroll
        for (int ks = 0; ks < 4; ++ks) {
            short8 fv;
#pragma unroll
            for (int j = 0; j < 8; ++j) {
                int kp = ks * 32 + q * 8 + j;
                fv[j] = (short)W[(size_t)kp * 192 + col];
            }
            bV[g][ks] = fv;
        }
    }

    const float bz  = bf2f(bi[u])       + bf2f(br[u]);
    const float brg = bf2f(bi[64 + u])  + bf2f(br[64 + u]);
    const float bih = bf2f(bi[128 + u]);
    const float brh = bf2f(br[128 + u]);
    const f32x4 Cz  = {bz,  bz,  bz,  bz};
    const f32x4 Cr  = {brg, brg, brg, brg};
    const f32x4 Chx = {bih, bih, bih, bih};
    const f32x4 Chr = {brh, brh, brh, brh};

    float hA[4], hB[4];
#pragma unroll
    for (int i = 0; i < 4; ++i) { hA[i] = 0.0f; hB[i] = 0.0f; }

    // prologue: P(0) for A and B; preload c = s(1)
    f32x4 PA0, PA1, PA2, PB0, PB1, PB2;
    {
        short8 s0 = *(const short8*)(sA);
        short8 s1 = *(const short8*)(sA + 32);
        short8 s2 = *(const short8*)(sA + 64);
        short8 s3 = *(const short8*)(sA + 96);
        PA0 = MFMA_B16(s0, bV[0][0], Cz);
        PA0 = MFMA_B16(s1, bV[0][1], PA0);
        PA0 = MFMA_B16(s2, bV[0][2], PA0);
        PA0 = MFMA_B16(s3, bV[0][3], PA0);
        PA1 = MFMA_B16(s0, bV[1][0], Cr);
        PA1 = MFMA_B16(s1, bV[1][1], PA1);
        PA1 = MFMA_B16(s2, bV[1][2], PA1);
        PA1 = MFMA_B16(s3, bV[1][3], PA1);
        PA2 = MFMA_B16(s0, bV[2][0], Chx);
        PA2 = MFMA_B16(s1, bV[2][1], PA2);
        PA2 = MFMA_B16(s2, bV[2][2], PA2);
        PA2 = MFMA_B16(s3, bV[2][3], PA2);
        short8 t0 = *(const short8*)(sB);
        short8 t1 = *(const short8*)(sB + 32);
        short8 t2 = *(const short8*)(sB + 64);
        short8 t3 = *(const short8*)(sB + 96);
        PB0 = MFMA_B16(t0, bV[0][0], Cz);
        PB0 = MFMA_B16(t1, bV[0][1], PB0);
        PB0 = MFMA_B16(t2, bV[0][2], PB0);
        PB0 = MFMA_B16(t3, bV[0][3], PB0);
        PB1 = MFMA_B16(t0, bV[1][0], Cr);
        PB1 = MFMA_B16(t1, bV[1][1], PB1);
        PB1 = MFMA_B16(t2, bV[1][2], PB1);
        PB1 = MFMA_B16(t3, bV[1][3], PB1);
        PB2 = MFMA_B16(t0, bV[2][0], Chx);
        PB2 = MFMA_B16(t1, bV[2][1], PB2);
        PB2 = MFMA_B16(t2, bV[2][2], PB2);
        PB2 = MFMA_B16(t3, bV[2][3], PB2);
    }
    short8 cA0, cA1, cA2, cA3, cB0, cB1, cB2, cB3;
    {
        const unsigned short* pa = sA + tstride;
        const unsigned short* pb = sB + tstride;
        cA0 = *(const short8*)(pa);
        cA1 = *(const short8*)(pa + 32);
        cA2 = *(const short8*)(pa + 64);
        cA3 = *(const short8*)(pa + 96);
        cB0 = *(const short8*)(pb);
        cB1 = *(const short8*)(pb + 32);
        cB2 = *(const short8*)(pb + 64);
        cB3 = *(const short8*)(pb + 96);
    }
    __syncthreads();

#pragma unroll 2
    for (int t = 0; t < 72; ++t) {
        const int cur = t & 1, nb = cur ^ 1;

        short8 fA0, fA1, fA2, fA3, fB0, fB1, fB2, fB3;
        const bool pf2 = (t < 70);
        if (pf2) {
            const unsigned short* pa = sA + (long long)(t + 2) * tstride;
            const unsigned short* pb = sB + (long long)(t + 2) * tstride;
            fA0 = *(const short8*)(pa);
            fA1 = *(const short8*)(pa + 32);
            fA2 = *(const short8*)(pa + 64);
            fA3 = *(const short8*)(pa + 96);
            fB0 = *(const short8*)(pb);
            fB1 = *(const short8*)(pb + 32);
            fB2 = *(const short8*)(pb + 64);
            fB3 = *(const short8*)(pb + 96);
        }

        const unsigned short* apA = &Ah[cur][ln][0];
        const unsigned short* apB = &Ah[cur][16 + ln][0];
        short8 a0A = *(const short8*)(apA + q * 8);
        short8 a1A = *(const short8*)(apA + 32 + q * 8);
        short8 a0B = *(const short8*)(apB + q * 8);
        short8 a1B = *(const short8*)(apB + 32 + q * 8);

        f32x4 azA = MFMA_B16(a0A, bU[0][0], PA0);
        azA = MFMA_B16(a1A, bU[0][1], azA);
        f32x4 arA = MFMA_B16(a0A, bU[1][0], PA1);
        arA = MFMA_B16(a1A, bU[1][1], arA);
        f32x4 ahrA = MFMA_B16(a0A, bU[2][0], Chr);
        ahrA = MFMA_B16(a1A, bU[2][1], ahrA);

        f32x4 azB = MFMA_B16(a0B, bU[0][0], PB0);
        azB = MFMA_B16(a1B, bU[0][1], azB);
        f32x4 arB = MFMA_B16(a0B, bU[1][0], PB1);
        arB = MFMA_B16(a1B, bU[1][1], arB);
        f32x4 ahrB = MFMA_B16(a0B, bU[2][0], Chr);
        ahrB = MFMA_B16(a1B, bU[2][1], ahrB);

#pragma unroll
        for (int i = 0; i < 4; ++i) {
            const int m = q * 4 + i;
            float zA = sigm_pre(azA[i]);
            float rA = sigm_pre(arA[i]);
            float hhA = tanh_pre(PA2[i] + rA * ahrA[i]);
            float hnA = hhA + zA * (hA[i] - hhA);
            hA[i] = hnA;
            Ah[nb][m][u] = f2bf(hnA);

            float zB = sigm_pre(azB[i]);
            float rB = sigm_pre(arB[i]);
            float hhB = tanh_pre(PB2[i] + rB * ahrB[i]);
            float hnB = hhB + zB * (hB[i] - hhB);
            hB[i] = hnB;
            Ah[nb][16 + m][u] = f2bf(hnB);
        }

        if (t < 71) {
            PA0 = MFMA_B16(cA0, bV[0][0], Cz);
            PA0 = MFMA_B16(cA1, bV[0][1], PA0);
            PA0 = MFMA_B16(cA2, bV[0][2], PA0);
            PA0 = MFMA_B16(cA3, bV[0][3], PA0);
            PA1 = MFMA_B16(cA0, bV[1][0], Cr);
            PA1 = MFMA_B16(cA1, bV[1][1], PA1);
            PA1 = MFMA_B16(cA2, bV[1][2], PA1);
            PA1 = MFMA_B16(cA3, bV[1][3], PA1);
            PA2 = MFMA_B16(cA0, bV[2][0], Chx);
            PA2 = MFMA_B16(cA1, bV[2][1], PA2);
            PA2 = MFMA_B16(cA2, bV[2][2], PA2);
            PA2 = MFMA_B16(cA3, bV[2][3], PA2);
            PB0 = MFMA_B16(cB0, bV[0][0], Cz);
            PB0 = MFMA_B16(cB1, bV[0][1], PB0);
            PB0 = MFMA_B16(cB2, bV[0][2], PB0);
            PB0 = MFMA_B16(cB3, bV[0][3], PB0);
            PB1 = MFMA_B16(cB0, bV[1][0], Cr);
            PB1 = MFMA_B16(cB1, bV[1][1], PB1);
            PB1 = MFMA_B16(cB2, bV[1][2], PB1);
            PB1 = MFMA_B16(cB3, bV[1][3], PB1);
            PB2 = MFMA_B16(cB0, bV[2][0], Chx);
            PB2 = MFMA_B16(cB1, bV[2][1], PB2);
            PB2 = MFMA_B16(cB2, bV[2][2], PB2);
            PB2 = MFMA_B16(cB3, bV[2][3], PB2);
        }
        if (pf2) {
            cA0 = fA0; cA1 = fA1; cA2 = fA2; cA3 = fA3;
            cB0 = fB0; cB1 = fB1; cB2 = fB2; cB3 = fB3;
        }
        __syncthreads();
    }

#pragma unroll
    for (int i = 0; i < 4; ++i) {
        const int m = q * 4 + i;
        feat[(size_t)(gb0 + m) * 128 + dir * 64 + u]      = hA[i];
        feat[(size_t)(gb0 + 16 + m) * 128 + dir * 64 + u] = hB[i];
    }
}

// ---------------------------------------------------------------------------
__global__ __launch_bounds__(256, 1)
void head_kernel(const float* __restrict__ feat,
                 const unsigned short* __restrict__ dW, const unsigned short* __restrict__ db,
                 const unsigned short* __restrict__ oW, const unsigned short* __restrict__ ob,
                 float* __restrict__ out)
{
    const int tid = threadIdx.x;
    const int b0  = blockIdx.x * 16;

    __shared__ __align__(16) unsigned short Wl[128][136];
    __shared__ __align__(16) float fs[16][128];
    __shared__ __align__(16) float hs[16][136];
    __shared__ __align__(16) float ls[16][32];

    for (int i = tid; i < 2048; i += 256) {
        const int k = i >> 4;
        const int c = (i & 15) * 8;
        *(int4*)&Wl[k][c] = *(const int4*)(dW + (size_t)k * 128 + c);
    }
    {
        const float4* src = (const float4*)(feat + (size_t)b0 * 128);
        float4* dst = (float4*)&fs[0][0];
        for (int i = tid; i < 512; i += 256) dst[i] = src[i];
    }
    __syncthreads();

    {
        const int row = tid >> 4;
        const int j0  = (tid & 15) * 8;
        float acc[8];
#pragma unroll
        for (int jj = 0; jj < 8; ++jj) acc[jj] = bf2f(db[j0 + jj]);
        for (int k = 0; k < 128; ++k) {
            float f = fs[row][k];
            short8 w = *(const short8*)&Wl[k][j0];
#pragma unroll
            for (int jj = 0; jj < 8; ++jj)
                acc[jj] += f * bf2f((unsigned short)w[jj]);
        }
#pragma unroll
        for (int jj = 0; jj < 8; ++jj) hs[row][j0 + jj] = fmaxf(acc[jj], 0.0f);
    }
    __syncthreads();

    for (int e = tid; e < 16 * 24; e += 256) {
        const int row = e / 24, l = e - 24 * row;
        float acc = bf2f(ob[l]);
        for (int k = 0; k < 128; ++k)
            acc += hs[row][k] * bf2f(oW[(size_t)k * 24 + l]);
        ls[row][l] = acc;
    }
    __syncthreads();

    for (int e = tid; e < 16 * 24; e += 256) {
        const int row = e / 24, l = e - 24 * row;
        float mx = ls[row][0];
#pragma unroll
        for (int k = 1; k < 24; ++k) mx = fmaxf(mx, ls[row][k]);
        float s = 0.0f;
#pragma unroll
        for (int k = 0; k < 24; ++k) s += __expf(ls[row][k] - mx);
        float v = __expf(ls[row][l] - mx) * rcp_f(s);
        out[(size_t)(b0 + row) * 24 + l] = v;
    }
}

// ---------------------------------------------------------------------------
extern "C" void kernel_launch(void* const* d_in, const int* in_sizes, int n_in,
                              void* d_out, int out_size, void* d_ws, size_t ws_size,
                              hipStream_t stream) {
    (void)in_sizes; (void)n_in; (void)out_size;

    static const int wc[20] = {
        1728, 12288, 192, 192,
        1728, 12288, 192, 192,
        24576, 12288, 192, 192,
        24576, 12288, 192, 192,
        16384, 128,
        3072, 24
    };

    WArgs a;
    int off = 0;
    for (int t = 0; t < 20; ++t) {
        a.src[t] = d_in[t + 3];
        a.off[t] = off;
        off += wc[t];
    }
    a.off[20] = off;

    const unsigned long long arena_bytes = 245952ull;
    const unsigned long long feat_bytes  = 4096ull * 128ull * 4ull;
    const unsigned long long seq_full    = 72ull * 4096ull * 128ull * 2ull;
    const unsigned long long fixed       = arena_bytes + feat_bytes;

    int nc = 32;
    for (int c = 1; c <= 32; c *= 2) {
        if (fixed + seq_full / (unsigned long long)c <= (unsigned long long)ws_size) { nc = c; break; }
    }
    const int bchunk = 4096 / nc;

    unsigned short* arena = (unsigned short*)d_ws;
    float* feat           = (float*)((char*)d_ws + arena_bytes);
    unsigned short* seq   = (unsigned short*)((char*)d_ws + fixed);

    convert_w<<<128, 256, 0, stream>>>(a, arena, (const unsigned short*)d_in[0]);

    const unsigned short* d1fW = arena + a.off[0];
    const unsigned short* d1fU = arena + a.off[1];
    const unsigned short* d1fbi= arena + a.off[2];
    const unsigned short* d1fbr= arena + a.off[3];
    const unsigned short* d1bW = arena + a.off[4];
    const unsigned short* d1bU = arena + a.off[5];
    const unsigned short* d1bbi= arena + a.off[6];
    const unsigned short* d1bbr= arena + a.off[7];
    const unsigned short* d2fW = arena + a.off[8];
    const unsigned short* d2fU = arena + a.off[9];
    const unsigned short* d2fbi= arena + a.off[10];
    const unsigned short* d2fbr= arena + a.off[11];
    const unsigned short* d2bW = arena + a.off[12];
    const unsigned short* d2bU = arena + a.off[13];
    const unsigned short* d2bbi= arena + a.off[14];
    const unsigned short* d2bbr= arena + a.off[15];
    const unsigned short* dW   = arena + a.off[16];
    const unsigned short* db   = arena + a.off[17];
    const unsigned short* oW   = arena + a.off[18];
    const unsigned short* ob   = arena + a.off[19];

    for (int c = 0; c < nc; ++c) {
        const int cb = c * bchunk;
        gru1_kernel<<<dim3(bchunk / 32, 2), 256, 0, stream>>>(
            d_in[0], d_in[1], d_in[2], cb, bchunk,
            d1fW, d1fU, d1fbi, d1fbr, d1bW, d1bU, d1bbi, d1bbr, seq);
        gru2_kernel<<<dim3(bchunk / 32, 2), 256, 0, stream>>>(
            seq, cb, bchunk,
            d2fW, d2fU, d2fbi, d2fbr, d2bW, d2bU, d2bbi, d2bbr, feat);
    }
    head_kernel<<<256, 256, 0, stream>>>(
        feat, dW, db, oW, ob, (float*)d_out);
}

// Round 15
// 266.948 us; speedup vs baseline: 1.1199x; 1.1199x over previous
//
#include <hip/hip_runtime.h>
#include <hip/hip_bf16.h>

typedef __attribute__((ext_vector_type(8))) short short8;
typedef __attribute__((ext_vector_type(4))) float f32x4;

#define MFMA_B16(a, b, c) __builtin_amdgcn_mfma_f32_16x16x32_bf16((a), (b), (c), 0, 0, 0)

__device__ __forceinline__ float bf2f(unsigned short u) {
    union { unsigned int i; float f; } v; v.i = ((unsigned int)u) << 16; return v.f;
}
__device__ __forceinline__ unsigned short f2bf(float f) {
    union { float f; unsigned int i; } v; v.f = f;
    unsigned int r = v.i + 0x7fffu + ((v.i >> 16) & 1u);
    return (unsigned short)(r >> 16);
}
// fast HW transcendentals; gate scale constants folded into weights at gather.
__device__ __forceinline__ float rcp_f(float x) { return __builtin_amdgcn_rcpf(x); }
__device__ __forceinline__ float sigm_pre(float x) {      // x = -log2(e)*(...)
    return rcp_f(1.0f + __builtin_amdgcn_exp2f(x));
}
__device__ __forceinline__ float tanh_pre(float x) {      // x = 2*log2(e)*(...)
    return 1.0f - 2.0f * rcp_f(__builtin_amdgcn_exp2f(x) + 1.0f);
}

#define NLOG2E (-1.4426950408889634f)
#define TLOG2E  (2.885390081777927f)

// dtype-agnostic element read
__device__ __forceinline__ float rdv(const void* p, size_t i, bool bf) {
    return bf ? bf2f(((const unsigned short*)p)[i]) : ((const float*)p)[i];
}

// probe 256 shorts of d_in[0] (N(0,1) data): bf16 vs fp32 discrimination
__device__ __forceinline__ bool probe_bf16(const unsigned short* p, int tid, int* s_cnt) {
    if (tid == 0) *s_cnt = 0;
    __syncthreads();
    unsigned short s = p[tid & 255];
    int e = (s >> 7) & 0xFF;
    if (tid < 256 && e >= 117 && e <= 137) atomicAdd(s_cnt, 1);
    __syncthreads();
    return *s_cnt >= 200;
}

// ---------------------------------------------------------------------------
// Layer 1: bidirectional GRU(64), relu candidate. 16 rows/block, h bf16 K=64,
// x hi/lo bf16 K=32 via LDS, depth-2 x prefetch. Weights read RAW from d_in
// (probe + convert + z/r scale folding inline). grid (bchunk/16, 2), block 256.
// ---------------------------------------------------------------------------
__global__ __launch_bounds__(256, 1)
void gru1_kernel(const void* __restrict__ X, const void* __restrict__ h0f,
                 const void* __restrict__ h0b, int cb, int bchunk,
                 const void* __restrict__ Wf, const void* __restrict__ Uf,
                 const void* __restrict__ bif, const void* __restrict__ brf,
                 const void* __restrict__ Wb, const void* __restrict__ Ub,
                 const void* __restrict__ bib, const void* __restrict__ brb,
                 unsigned short* __restrict__ seq)
{
    const int tid  = threadIdx.x;
    const int lane = tid & 63;
    const int wv   = tid >> 6;
    const int q    = lane >> 4;
    const int ln   = lane & 15;
    const int dir  = blockIdx.y;
    const int lb0  = blockIdx.x * 16;
    const int gb0  = cb + lb0;
    const int u    = wv * 16 + ln;

    const void* W  = dir ? Wb  : Wf;
    const void* U  = dir ? Ub  : Uf;
    const void* bi = dir ? bib : bif;
    const void* br = dir ? brb : brf;
    const void* h0 = dir ? h0b : h0f;

    __shared__ __align__(16) unsigned short Ah[2][16][72];
    __shared__ __align__(16) unsigned short Ax[2][16][40];
    __shared__ int s_cnt;

    const bool xbf = probe_bf16((const unsigned short*)X, tid, &s_cnt);

    {
        unsigned short* p = &Ax[0][0][0];
        for (int i = tid; i < 2 * 16 * 40; i += 256) p[i] = 0;
    }
    __syncthreads();

    {
        const int tx0 = dir ? 71 : 0;
        if (tid < 144) {
            int r = tid / 9, k = tid - 9 * r;
            size_t idx = ((size_t)(gb0 + r) * 72 + tx0) * 9 + k;
            unsigned short hv, lv;
            if (xbf) { hv = ((const unsigned short*)X)[idx]; lv = 0; }
            else { float v = ((const float*)X)[idx]; hv = f2bf(v); lv = f2bf(v - bf2f(hv)); }
            Ax[0][r][2 * k]     = hv;
            Ax[0][r][2 * k + 1] = lv;
        }
    }

    // B-fragments: inline convert + gate scaling (z,r: -log2e; cand: 1 for relu)
    short8 bU[3][2];
    short8 bW[3];
#pragma unroll
    for (int g = 0; g < 3; ++g) {
        const int col = g * 64 + u;
        const float gs = (g < 2) ? NLOG2E : 1.0f;
#pragma unroll
        for (int ks = 0; ks < 2; ++ks) {
            short8 f;
#pragma unroll
            for (int j = 0; j < 8; ++j) {
                int kp = ks * 32 + q * 8 + j;
                f[j] = (short)f2bf(rdv(U, (size_t)kp * 192 + col, xbf) * gs);
            }
            bU[g][ks] = f;
        }
        short8 fw;
#pragma unroll
        for (int j = 0; j < 8; ++j) {
            int kp = q * 8 + j;
            fw[j] = (kp < 18) ? (short)f2bf(rdv(W, (size_t)(kp >> 1) * 192 + col, xbf) * gs)
                              : (short)0;
        }
        bW[g] = fw;
    }

    const float bz  = NLOG2E * (rdv(bi, u, xbf)      + rdv(br, u, xbf));
    const float brg = NLOG2E * (rdv(bi, 64 + u, xbf) + rdv(br, 64 + u, xbf));
    const float bih = rdv(bi, 128 + u, xbf);
    const float brh = rdv(br, 128 + u, xbf);
    const f32x4 Cz  = {bz,  bz,  bz,  bz};
    const f32x4 Cr  = {brg, brg, brg, brg};
    const f32x4 Chx = {bih, bih, bih, bih};
    const f32x4 Chr = {brh, brh, brh, brh};

    float hreg[4];
#pragma unroll
    for (int i = 0; i < 4; ++i) {
        int m = q * 4 + i;
        float hv = rdv(h0, (size_t)(gb0 + m) * 64 + u, xbf);
        hreg[i] = hv;
        Ah[0][m][u] = f2bf(hv);
    }

    const int r2 = tid >> 3, c2 = tid & 7;
    const int r0x = tid / 9, k0x = tid - 9 * r0x;

    // depth-2 x pipeline: ch/cl hold x(t+1); preload x(1)
    unsigned short ch = 0, cl = 0;
    if (tid < 144) {
        const int tx = dir ? 70 : 1;
        size_t idx = ((size_t)(gb0 + r0x) * 72 + tx) * 9 + k0x;
        if (xbf) { ch = ((const unsigned short*)X)[idx]; cl = 0; }
        else { float v = ((const float*)X)[idx]; ch = f2bf(v); cl = f2bf(v - bf2f(ch)); }
    }
    __syncthreads();

#pragma unroll 2
    for (int t = 0; t < 72; ++t) {
        const int cur = t & 1, nb = cur ^ 1;

        unsigned short fh = 0, fl = 0;
        if (t < 70 && tid < 144) {
            const int tx = dir ? (69 - t) : (t + 2);
            size_t idx = ((size_t)(gb0 + r0x) * 72 + tx) * 9 + k0x;
            if (xbf) { fh = ((const unsigned short*)X)[idx]; fl = 0; }
            else { float v = ((const float*)X)[idx]; fh = f2bf(v); fl = f2bf(v - bf2f(fh)); }
        }

        if (t > 0 && tid < 128) {
            const int tw = dir ? (71 - (t - 1)) : (t - 1);
            int4 v = *(const int4*)&Ah[cur][r2][c2 * 8];
            *(int4*)(seq + ((size_t)tw * bchunk + lb0 + r2) * 128 + dir * 64 + c2 * 8) = v;
        }

        const unsigned short* ap = &Ah[cur][ln][0];
        short8 a0 = *(const short8*)(ap + q * 8);
        short8 a1 = *(const short8*)(ap + 32 + q * 8);
        short8 ax = *(const short8*)(&Ax[cur][ln][q * 8]);
        f32x4 az  = MFMA_B16(ax, bW[0], Cz);
        az        = MFMA_B16(a0, bU[0][0], az);
        az        = MFMA_B16(a1, bU[0][1], az);
        f32x4 ar  = MFMA_B16(ax, bW[1], Cr);
        ar        = MFMA_B16(a0, bU[1][0], ar);
        ar        = MFMA_B16(a1, bU[1][1], ar);
        f32x4 ahx = MFMA_B16(ax, bW[2], Chx);
        f32x4 ahr = MFMA_B16(a0, bU[2][0], Chr);
        ahr       = MFMA_B16(a1, bU[2][1], ahr);

#pragma unroll
        for (int i = 0; i < 4; ++i) {
            const int m = q * 4 + i;
            float z = sigm_pre(az[i]);
            float r = sigm_pre(ar[i]);
            float pre = ahx[i] + r * ahr[i];
            float hh = fmaxf(pre, 0.0f);
            float hn = hh + z * (hreg[i] - hh);
            hreg[i] = hn;
            Ah[nb][m][u] = f2bf(hn);
        }

        if (t < 71 && tid < 144) {
            Ax[nb][r0x][2 * k0x]     = ch;
            Ax[nb][r0x][2 * k0x + 1] = cl;
        }
        ch = fh; cl = fl;
        __syncthreads();
    }

    if (tid < 128) {
        const int tw = dir ? 0 : 71;
        int4 v = *(const int4*)&Ah[0][r2][c2 * 8];
        *(int4*)(seq + ((size_t)tw * bchunk + lb0 + r2) * 128 + dir * 64 + c2 * 8) = v;
    }
}

// ---------------------------------------------------------------------------
// Layer 2: bidirectional GRU(64), tanh (pre-scaled). Raw weights inline-
// converted; seq A-frags direct from global, depth-2 prefetch; projections
// pre-barrier. grid (bchunk/16, 2), block 256.
// ---------------------------------------------------------------------------
__global__ __launch_bounds__(256, 1)
void gru2_kernel(const unsigned short* __restrict__ seq, int cb, int bchunk,
                 const void* __restrict__ probe,
                 const void* __restrict__ W2f, const void* __restrict__ U2f,
                 const void* __restrict__ bi2f, const void* __restrict__ br2f,
                 const void* __restrict__ W2b, const void* __restrict__ U2b,
                 const void* __restrict__ bi2b, const void* __restrict__ br2b,
                 float* __restrict__ feat)
{
    const int tid  = threadIdx.x;
    const int lane = tid & 63;
    const int wv   = tid >> 6;
    const int q    = lane >> 4;
    const int ln   = lane & 15;
    const int dir  = blockIdx.y;
    const int lb0  = blockIdx.x * 16;
    const int gb0  = cb + lb0;
    const int u    = wv * 16 + ln;

    const void* W  = dir ? W2b  : W2f;
    const void* U  = dir ? U2b  : U2f;
    const void* bi = dir ? bi2b : bi2f;
    const void* br = dir ? br2b : br2f;

    __shared__ __align__(16) unsigned short Ah[2][16][72];
    __shared__ int s_cnt;

    const bool xbf = probe_bf16((const unsigned short*)probe, tid, &s_cnt);

    {
        unsigned short* p = &Ah[0][0][0];
        for (int i = tid; i < 16 * 72; i += 256) p[i] = 0;
    }

    const long long tstride = (long long)bchunk * 128 * (dir ? -1 : 1);
    const unsigned short* sptr0 = seq + ((size_t)(lb0 + ln)) * 128 + q * 8
                                + (dir ? 71ll * bchunk * 128 : 0);

    short8 bU[3][2];
    short8 bV[3][4];
#pragma unroll
    for (int g = 0; g < 3; ++g) {
        const int col = g * 64 + u;
        const float gs = (g < 2) ? NLOG2E : TLOG2E;
#pragma unroll
        for (int ks = 0; ks < 2; ++ks) {
            short8 f;
#pragma unroll
            for (int j = 0; j < 8; ++j) {
                int kp = ks * 32 + q * 8 + j;
                f[j] = (short)f2bf(rdv(U, (size_t)kp * 192 + col, xbf) * gs);
            }
            bU[g][ks] = f;
        }
#pragma unroll
        for (int ks = 0; ks < 4; ++ks) {
            short8 fv;
#pragma unroll
            for (int j = 0; j < 8; ++j) {
                int kp = ks * 32 + q * 8 + j;
                fv[j] = (short)f2bf(rdv(W, (size_t)kp * 192 + col, xbf) * gs);
            }
            bV[g][ks] = fv;
        }
    }

    const float bz  = NLOG2E * (rdv(bi, u, xbf)      + rdv(br, u, xbf));
    const float brg = NLOG2E * (rdv(bi, 64 + u, xbf) + rdv(br, 64 + u, xbf));
    const float bih = TLOG2E * rdv(bi, 128 + u, xbf);
    const float brh = TLOG2E * rdv(br, 128 + u, xbf);
    const f32x4 Cz  = {bz,  bz,  bz,  bz};
    const f32x4 Cr  = {brg, brg, brg, brg};
    const f32x4 Chx = {bih, bih, bih, bih};
    const f32x4 Chr = {brh, brh, brh, brh};

    float hreg[4];
#pragma unroll
    for (int i = 0; i < 4; ++i) hreg[i] = 0.0f;

    // prologue: P(0) from s(0); preload c = s(1)
    f32x4 P0, P1, P2;
    {
        const unsigned short* sp = sptr0;
        short8 s0 = *(const short8*)(sp);
        short8 s1 = *(const short8*)(sp + 32);
        short8 s2 = *(const short8*)(sp + 64);
        short8 s3 = *(const short8*)(sp + 96);
        P0 = MFMA_B16(s0, bV[0][0], Cz);
        P0 = MFMA_B16(s1, bV[0][1], P0);
        P0 = MFMA_B16(s2, bV[0][2], P0);
        P0 = MFMA_B16(s3, bV[0][3], P0);
        P1 = MFMA_B16(s0, bV[1][0], Cr);
        P1 = MFMA_B16(s1, bV[1][1], P1);
        P1 = MFMA_B16(s2, bV[1][2], P1);
        P1 = MFMA_B16(s3, bV[1][3], P1);
        P2 = MFMA_B16(s0, bV[2][0], Chx);
        P2 = MFMA_B16(s1, bV[2][1], P2);
        P2 = MFMA_B16(s2, bV[2][2], P2);
        P2 = MFMA_B16(s3, bV[2][3], P2);
    }
    short8 c0, c1, c2, c3;
    {
        const unsigned short* sp = sptr0 + tstride;
        c0 = *(const short8*)(sp);
        c1 = *(const short8*)(sp + 32);
        c2 = *(const short8*)(sp + 64);
        c3 = *(const short8*)(sp + 96);
    }
    __syncthreads();

#pragma unroll 2
    for (int t = 0; t < 72; ++t) {
        const int cur = t & 1, nb = cur ^ 1;

        short8 f0, f1, f2, f3;
        const bool pf2 = (t < 70);
        if (pf2) {
            const unsigned short* sp = sptr0 + (long long)(t + 2) * tstride;
            f0 = *(const short8*)(sp);
            f1 = *(const short8*)(sp + 32);
            f2 = *(const short8*)(sp + 64);
            f3 = *(const short8*)(sp + 96);
        }

        const unsigned short* ap = &Ah[cur][ln][0];
        short8 a0 = *(const short8*)(ap + q * 8);
        short8 a1 = *(const short8*)(ap + 32 + q * 8);
        f32x4 az  = MFMA_B16(a0, bU[0][0], P0);
        az        = MFMA_B16(a1, bU[0][1], az);
        f32x4 ar  = MFMA_B16(a0, bU[1][0], P1);
        ar        = MFMA_B16(a1, bU[1][1], ar);
        f32x4 ahr = MFMA_B16(a0, bU[2][0], Chr);
        ahr       = MFMA_B16(a1, bU[2][1], ahr);
        f32x4 ahx = P2;

#pragma unroll
        for (int i = 0; i < 4; ++i) {
            const int m = q * 4 + i;
            float z = sigm_pre(az[i]);
            float r = sigm_pre(ar[i]);
            float pre = ahx[i] + r * ahr[i];
            float hh = tanh_pre(pre);
            float hn = hh + z * (hreg[i] - hh);
            hreg[i] = hn;
            Ah[nb][m][u] = f2bf(hn);
        }

        if (t < 71) {
            P0 = MFMA_B16(c0, bV[0][0], Cz);
            P0 = MFMA_B16(c1, bV[0][1], P0);
            P0 = MFMA_B16(c2, bV[0][2], P0);
            P0 = MFMA_B16(c3, bV[0][3], P0);
            P1 = MFMA_B16(c0, bV[1][0], Cr);
            P1 = MFMA_B16(c1, bV[1][1], P1);
            P1 = MFMA_B16(c2, bV[1][2], P1);
            P1 = MFMA_B16(c3, bV[1][3], P1);
            P2 = MFMA_B16(c0, bV[2][0], Chx);
            P2 = MFMA_B16(c1, bV[2][1], P2);
            P2 = MFMA_B16(c2, bV[2][2], P2);
            P2 = MFMA_B16(c3, bV[2][3], P2);
        }
        if (pf2) { c0 = f0; c1 = f1; c2 = f2; c3 = f3; }
        __syncthreads();
    }

#pragma unroll
    for (int i = 0; i < 4; ++i) {
        const int m = q * 4 + i;
        feat[(size_t)(gb0 + m) * 128 + dir * 64 + u] = hreg[i];
    }
}

// ---------------------------------------------------------------------------
// Head: raw weights inline-converted during LDS stage.
// ---------------------------------------------------------------------------
__global__ __launch_bounds__(256, 1)
void head_kernel(const float* __restrict__ feat, const void* __restrict__ probe,
                 const void* __restrict__ dW, const void* __restrict__ db,
                 const void* __restrict__ oW, const void* __restrict__ ob,
                 float* __restrict__ out)
{
    const int tid = threadIdx.x;
    const int b0  = blockIdx.x * 16;

    __shared__ __align__(16) unsigned short Wl[128][136];
    __shared__ __align__(16) float fs[16][128];
    __shared__ __align__(16) float hs[16][136];
    __shared__ __align__(16) float ls[16][32];
    __shared__ int s_cnt;

    const bool bf = probe_bf16((const unsigned short*)probe, tid, &s_cnt);

    for (int i = tid; i < 2048; i += 256) {
        const int k = i >> 4;
        const int c = (i & 15) * 8;
        if (bf) {
            *(int4*)&Wl[k][c] = *(const int4*)((const unsigned short*)dW + (size_t)k * 128 + c);
        } else {
            const float* s = (const float*)dW + (size_t)k * 128 + c;
#pragma unroll
            for (int jj = 0; jj < 8; ++jj) Wl[k][c + jj] = f2bf(s[jj]);
        }
    }
    {
        const float4* src = (const float4*)(feat + (size_t)b0 * 128);
        float4* dst = (float4*)&fs[0][0];
        for (int i = tid; i < 512; i += 256) dst[i] = src[i];
    }
    __syncthreads();

    {
        const int row = tid >> 4;
        const int j0  = (tid & 15) * 8;
        float acc[8];
#pragma unroll
        for (int jj = 0; jj < 8; ++jj) acc[jj] = rdv(db, j0 + jj, bf);
        for (int k = 0; k < 128; ++k) {
            float f = fs[row][k];
            short8 w = *(const short8*)&Wl[k][j0];
#pragma unroll
            for (int jj = 0; jj < 8; ++jj)
                acc[jj] += f * bf2f((unsigned short)w[jj]);
        }
#pragma unroll
        for (int jj = 0; jj < 8; ++jj) hs[row][j0 + jj] = fmaxf(acc[jj], 0.0f);
    }
    __syncthreads();

    for (int e = tid; e < 16 * 24; e += 256) {
        const int row = e / 24, l = e - 24 * row;
        float acc = rdv(ob, l, bf);
        for (int k = 0; k < 128; ++k)
            acc += hs[row][k] * rdv(oW, (size_t)k * 24 + l, bf);
        ls[row][l] = acc;
    }
    __syncthreads();

    for (int e = tid; e < 16 * 24; e += 256) {
        const int row = e / 24, l = e - 24 * row;
        float mx = ls[row][0];
#pragma unroll
        for (int k = 1; k < 24; ++k) mx = fmaxf(mx, ls[row][k]);
        float s = 0.0f;
#pragma unroll
        for (int k = 0; k < 24; ++k) s += __expf(ls[row][k] - mx);
        float v = __expf(ls[row][l] - mx) * rcp_f(s);
        out[(size_t)(b0 + row) * 24 + l] = v;
    }
}

// ---------------------------------------------------------------------------
extern "C" void kernel_launch(void* const* d_in, const int* in_sizes, int n_in,
                              void* d_out, int out_size, void* d_ws, size_t ws_size,
                              hipStream_t stream) {
    (void)in_sizes; (void)n_in; (void)out_size;

    // ws layout: [feat fp32 2 MB][seq chunk bf16]
    const unsigned long long feat_bytes = 4096ull * 128ull * 4ull;
    const unsigned long long seq_full   = 72ull * 4096ull * 128ull * 2ull;

    int nc = 32;
    for (int c = 1; c <= 32; c *= 2) {
        if (feat_bytes + seq_full / (unsigned long long)c <= (unsigned long long)ws_size) { nc = c; break; }
    }
    const int bchunk = 4096 / nc;

    float* feat         = (float*)d_ws;
    unsigned short* seq = (unsigned short*)((char*)d_ws + feat_bytes);

    for (int c = 0; c < nc; ++c) {
        const int cb = c * bchunk;
        gru1_kernel<<<dim3(bchunk / 16, 2), 256, 0, stream>>>(
            d_in[0], d_in[1], d_in[2], cb, bchunk,
            d_in[3], d_in[4], d_in[5], d_in[6],
            d_in[7], d_in[8], d_in[9], d_in[10], seq);
        gru2_kernel<<<dim3(bchunk / 16, 2), 256, 0, stream>>>(
            seq, cb, bchunk, d_in[0],
            d_in[11], d_in[12], d_in[13], d_in[14],
            d_in[15], d_in[16], d_in[17], d_in[18], feat);
    }
    head_kernel<<<256, 256, 0, stream>>>(
        feat, d_in[0], d_in[19], d_in[20], d_in[21], d_in[22], (float*)d_out);
}